// Round 4
// baseline (4648.005 us; speedup 1.0000x reference)
//
#include <hip/hip_runtime.h>

// GAE encoder: 2-layer GCN on MI355X (gfx950).
// Pipeline: hist -> scan(3) -> dinv -> fill CSR -> [gemm+scale(bf16 out) -> aggregate] x2
// Aggregation gathers bf16 rows (halved traffic) with 4 loads in flight per wave.

typedef unsigned int uint;

// ---------- bf16 helpers (bit-level, RNE pack) ----------
__device__ __forceinline__ float bf_lo(uint v) { return __uint_as_float(v << 16); }
__device__ __forceinline__ float bf_hi(uint v) { return __uint_as_float(v & 0xffff0000u); }
__device__ __forceinline__ uint pack_bf16(float x, float y) {
    uint bx = __float_as_uint(x), by = __float_as_uint(y);
    bx += 0x7fffu + ((bx >> 16) & 1u);
    by += 0x7fffu + ((by >> 16) & 1u);
    return (bx >> 16) | (by & 0xffff0000u);
}

// ---------------- CSR build ----------------

__global__ __launch_bounds__(256) void hist_kernel(const int4* __restrict__ col4,
                                                   int* __restrict__ counts, int E4) {
    int i = blockIdx.x * 256 + threadIdx.x;
    if (i < E4) {
        int4 c = col4[i];
        atomicAdd(&counts[c.x], 1);
        atomicAdd(&counts[c.y], 1);
        atomicAdd(&counts[c.z], 1);
        atomicAdd(&counts[c.w], 1);
    }
}

// exclusive scan, phase A: per-block (1024 elems) Hillis-Steele
__global__ __launch_bounds__(1024) void scan_a(const int* __restrict__ counts,
                                               int* __restrict__ rp,
                                               int* __restrict__ bsums, int n) {
    __shared__ int s[2][1024];
    int t = threadIdx.x;
    int i = blockIdx.x * 1024 + t;
    int v = (i < n) ? counts[i] : 0;
    s[0][t] = v;
    __syncthreads();
    int p = 0;
    for (int d = 1; d < 1024; d <<= 1) {
        int val = s[p][t] + ((t >= d) ? s[p][t - d] : 0);
        s[p ^ 1][t] = val;
        p ^= 1;
        __syncthreads();
    }
    if (i < n) rp[i] = s[p][t] - v;
    if (t == 1023) bsums[blockIdx.x] = s[p][t];
}

__global__ __launch_bounds__(128) void scan_b(int* __restrict__ bsums, int nb) {
    __shared__ int s[2][128];
    int t = threadIdx.x;
    int v = (t < nb) ? bsums[t] : 0;
    s[0][t] = v;
    __syncthreads();
    int p = 0;
    for (int d = 1; d < 128; d <<= 1) {
        int val = s[p][t] + ((t >= d) ? s[p][t - d] : 0);
        s[p ^ 1][t] = val;
        p ^= 1;
        __syncthreads();
    }
    if (t < nb) bsums[t] = s[p][t] - v;
}

__global__ __launch_bounds__(256) void scan_c(int* __restrict__ rp,
                                              const int* __restrict__ bsums, int n, int E) {
    int i = blockIdx.x * 256 + threadIdx.x;
    if (i < n)       rp[i] += bsums[i >> 10];
    else if (i == n) rp[n] = E;
}

__global__ __launch_bounds__(256) void dinv_kernel(const int* __restrict__ counts,
                                                   float* __restrict__ dinv, int n) {
    int i = blockIdx.x * 256 + threadIdx.x;
    if (i < n) dinv[i] = rsqrtf((float)(counts[i] + 1)); // +1 = self loop
}

__global__ __launch_bounds__(256) void fill_kernel(const int* __restrict__ row,
                                                   const int* __restrict__ col,
                                                   const int* __restrict__ rp,
                                                   int* __restrict__ fill,
                                                   int* __restrict__ csr, int E) {
    int i = blockIdx.x * 256 + threadIdx.x;
    if (i < E) {
        int c = col[i];
        int p = rp[c] + atomicAdd(&fill[c], 1);
        csr[p] = row[i];
    }
}

// ---------------- GEMM: out[m][n] = bf16( dinv[m] * sum_k X[m][k] * W[k][n] ) ----------------
// K=128. f32 VALU (no fp32 MFMA). X tile 64x(128+pad) in LDS; W staged in 32-k chunks in LDS.
// Micro-tile 4 rows x (NC/16) cols per thread; 256 threads -> 64 rows, NC cols per block.

template <int NC, bool BF16_IN>
__global__ __launch_bounds__(256) void gemm_scale(const void* __restrict__ Xv,
                                                  const float* __restrict__ W,
                                                  const float* __restrict__ dinv,
                                                  uint* __restrict__ out, int M) {
    constexpr int K = 128, BM = 64, PAD = 132, CPT = NC / 16;
    __shared__ float xs[BM * PAD];
    __shared__ float ws[32 * NC];

    int tid = threadIdx.x;
    int block_row = blockIdx.x * BM;

    // stage X tile
    if (BF16_IN) {
        const uint* X = (const uint*)Xv;          // row = 64 uints (128 bf16)
        int r = tid >> 5, c = tid & 31;           // c -> bf16 cols c*4..c*4+3
#pragma unroll
        for (int p = 0; p < 8; ++p) {
            int rr = r + p * 8;
            int gr = block_row + rr;
            if (gr > M - 1) gr = M - 1;
            uint2 v = *(const uint2*)(X + (size_t)gr * 64 + c * 2);
            float* d = xs + rr * PAD + c * 4;
            d[0] = bf_lo(v.x); d[1] = bf_hi(v.x);
            d[2] = bf_lo(v.y); d[3] = bf_hi(v.y);
        }
    } else {
        const float* X = (const float*)Xv;
        int r = tid >> 5, k4 = tid & 31;
#pragma unroll
        for (int p = 0; p < 8; ++p) {
            int rr = r + p * 8;
            int gr = block_row + rr;
            if (gr > M - 1) gr = M - 1;
            float4 v = *(const float4*)(X + (size_t)gr * K + k4 * 4);
            *(float4*)(xs + rr * PAD + k4 * 4) = v;
        }
    }

    int tc = tid & 15;   // col group
    int tr = tid >> 4;   // row group (0..15), 4 rows each

    float acc[4][CPT];
#pragma unroll
    for (int i = 0; i < 4; ++i)
#pragma unroll
        for (int j = 0; j < CPT; ++j) acc[i][j] = 0.0f;

    constexpr int F4PT = NC / 32;                 // float4s per thread per W chunk

#pragma unroll
    for (int kc = 0; kc < K / 32; ++kc) {
        // stage W chunk [32][NC]
        {
            const float4* src = (const float4*)(W + (size_t)kc * 32 * NC);
            float4* dst = (float4*)ws;
#pragma unroll
            for (int i = 0; i < F4PT; ++i) dst[tid + i * 256] = src[tid + i * 256];
        }
        __syncthreads();

#pragma unroll
        for (int k4 = 0; k4 < 8; ++k4) {
            float4 xa[4];
#pragma unroll
            for (int i = 0; i < 4; ++i)
                xa[i] = *(const float4*)(xs + (tr * 4 + i) * PAD + kc * 32 + k4 * 4);
#pragma unroll
            for (int kk = 0; kk < 4; ++kk) {
                float wv[CPT];
#pragma unroll
                for (int m = 0; m < CPT / 4; ++m) {
                    float4 w4 = *(const float4*)(ws + (k4 * 4 + kk) * NC + tc * CPT + m * 4);
                    wv[m * 4 + 0] = w4.x; wv[m * 4 + 1] = w4.y;
                    wv[m * 4 + 2] = w4.z; wv[m * 4 + 3] = w4.w;
                }
#pragma unroll
                for (int i = 0; i < 4; ++i) {
                    float xv = (&xa[i].x)[kk];
#pragma unroll
                    for (int j = 0; j < CPT; ++j) acc[i][j] = fmaf(xv, wv[j], acc[i][j]);
                }
            }
        }
        __syncthreads();
    }

    // epilogue: scale by dinv, pack bf16 pairs
#pragma unroll
    for (int i = 0; i < 4; ++i) {
        int r = block_row + tr * 4 + i;
        if (r < M) {
            float di = dinv[r];
            uint pk[CPT / 2];
#pragma unroll
            for (int j = 0; j < CPT / 2; ++j)
                pk[j] = pack_bf16(acc[i][2 * j] * di, acc[i][2 * j + 1] * di);
            uint* dst = out + (size_t)r * (NC / 2) + tc * (CPT / 2);
            if (CPT == 8)      *(uint4*)dst = *(uint4*)pk;
            else if (CPT == 4) *(uint2*)dst = *(uint2*)pk;
        }
    }
}

// ---------------- Aggregation ----------------
// layer1: h[c] = bf16( relu(dinv[c]*(xws[c] + sum_src xws[src]) + b) ), 128 cols (64 uints), wave/node
// 4 gathers in flight per wave.

__global__ __launch_bounds__(256) void agg128(const uint* __restrict__ xws,
                                              const int* __restrict__ rp,
                                              const int* __restrict__ csr,
                                              const float* __restrict__ dinv,
                                              const float* __restrict__ bias,
                                              uint* __restrict__ h, int n) {
    int gid  = blockIdx.x * 256 + threadIdx.x;
    int node = gid >> 6;
    int lane = gid & 63;
    if (node >= n) return;

    uint self = xws[(size_t)node * 64 + lane];
    float ax = bf_lo(self), ay = bf_hi(self);

    int beg = rp[node], end = rp[node + 1];
    int e = beg;
    for (; e + 4 <= end; e += 4) {
        int s0 = csr[e], s1 = csr[e + 1], s2 = csr[e + 2], s3 = csr[e + 3];
        uint v0 = xws[(size_t)s0 * 64 + lane];
        uint v1 = xws[(size_t)s1 * 64 + lane];
        uint v2 = xws[(size_t)s2 * 64 + lane];
        uint v3 = xws[(size_t)s3 * 64 + lane];
        ax += bf_lo(v0) + bf_lo(v1) + bf_lo(v2) + bf_lo(v3);
        ay += bf_hi(v0) + bf_hi(v1) + bf_hi(v2) + bf_hi(v3);
    }
    for (; e < end; ++e) {
        uint v = xws[(size_t)csr[e] * 64 + lane];
        ax += bf_lo(v);
        ay += bf_hi(v);
    }

    float  di = dinv[node];
    float2 b  = ((const float2*)bias)[lane];
    float ox = fmaxf(fmaf(di, ax, b.x), 0.0f);
    float oy = fmaxf(fmaf(di, ay, b.y), 0.0f);
    h[(size_t)node * 64 + lane] = pack_bf16(ox, oy);
}

// layer2: out = dinv*(self + sum) + b, 64 cols (32 uints), half-wave per node, f32 output.

__global__ __launch_bounds__(256) void agg64(const uint* __restrict__ xws,
                                             const int* __restrict__ rp,
                                             const int* __restrict__ csr,
                                             const float* __restrict__ dinv,
                                             const float* __restrict__ bias,
                                             float* __restrict__ out, int n) {
    int gid  = blockIdx.x * 256 + threadIdx.x;
    int node = gid >> 5;
    int l    = gid & 31;
    if (node >= n) return;

    uint self = xws[(size_t)node * 32 + l];
    float ax = bf_lo(self), ay = bf_hi(self);

    int beg = rp[node], end = rp[node + 1];
    int e = beg;
    for (; e + 4 <= end; e += 4) {
        int s0 = csr[e], s1 = csr[e + 1], s2 = csr[e + 2], s3 = csr[e + 3];
        uint v0 = xws[(size_t)s0 * 32 + l];
        uint v1 = xws[(size_t)s1 * 32 + l];
        uint v2 = xws[(size_t)s2 * 32 + l];
        uint v3 = xws[(size_t)s3 * 32 + l];
        ax += bf_lo(v0) + bf_lo(v1) + bf_lo(v2) + bf_lo(v3);
        ay += bf_hi(v0) + bf_hi(v1) + bf_hi(v2) + bf_hi(v3);
    }
    for (; e < end; ++e) {
        uint v = xws[(size_t)csr[e] * 32 + l];
        ax += bf_lo(v);
        ay += bf_hi(v);
    }

    float  di = dinv[node];
    float2 b  = ((const float2*)bias)[l];
    float2 o;
    o.x = fmaf(di, ax, b.x);
    o.y = fmaf(di, ay, b.y);
    ((float2*)out)[(size_t)node * 32 + l] = o;
}

// ---------------- launch ----------------

static inline size_t align512(size_t x) { return (x + 511) & ~(size_t)511; }

extern "C" void kernel_launch(void* const* d_in, const int* in_sizes, int n_in,
                              void* d_out, int out_size, void* d_ws, size_t ws_size,
                              hipStream_t stream) {
    const float* x   = (const float*)d_in[0];
    const int*   ei  = (const int*)d_in[1];
    const float* W1  = (const float*)d_in[2];
    const float* b1  = (const float*)d_in[3];
    const float* W2  = (const float*)d_in[4];
    const float* b2  = (const float*)d_in[5];
    float*       out = (float*)d_out;

    const int N = in_sizes[0] / 128;   // 100000
    const int E = in_sizes[1] / 2;     // 1600000
    const int* row = ei;
    const int* col = ei + E;

    // workspace carve-up
    char* w = (char*)d_ws;
    size_t off = 0;
    auto take = [&](size_t bytes) { void* p = w + off; off = align512(off + bytes); return p; };
    int*   counts = (int*)  take((size_t)N * 4);
    int*   fill   = (int*)  take((size_t)N * 4);
    size_t zero_bytes = off;                     // counts + fill must start at 0
    int*   rp     = (int*)  take((size_t)(N + 1) * 4);
    int*   bsums  = (int*)  take(512);
    float* dinv   = (float*)take((size_t)N * 4);
    int*   csr    = (int*)  take((size_t)E * 4);
    uint*  xws    = (uint*) take((size_t)N * 64 * 4);   // bf16-packed [N,128] (layer1) / reused [N,64] (layer2)
    uint*  h      = (uint*) take((size_t)N * 64 * 4);   // bf16-packed [N,128]
    (void)ws_size;

    hipMemsetAsync(d_ws, 0, zero_bytes, stream);

    const int nb = (N + 1023) / 1024;

    hist_kernel<<<(E / 4 + 255) / 256, 256, 0, stream>>>((const int4*)col, counts, E / 4);
    scan_a<<<nb, 1024, 0, stream>>>(counts, rp, bsums, N);
    scan_b<<<1, 128, 0, stream>>>(bsums, nb);
    scan_c<<<(N + 256) / 256, 256, 0, stream>>>(rp, bsums, N, E);
    dinv_kernel<<<(N + 255) / 256, 256, 0, stream>>>(counts, dinv, N);
    fill_kernel<<<(E + 255) / 256, 256, 0, stream>>>(row, col, rp, fill, csr, E);

    // layer 1
    gemm_scale<128, false><<<(N + 63) / 64, 256, 0, stream>>>(x, W1, dinv, xws, N);
    agg128<<<(N + 3) / 4, 256, 0, stream>>>(xws, rp, csr, dinv, b1, h, N);

    // layer 2
    gemm_scale<64, true><<<(N + 63) / 64, 256, 0, stream>>>(h, W2, dinv, xws, N);
    agg64<<<(N + 7) / 8, 256, 0, stream>>>(xws, rp, csr, dinv, b2, out, N);
}

// Round 5
// 474.855 us; speedup vs baseline: 9.7883x; 9.7883x over previous
//
#include <hip/hip_runtime.h>

// GAE encoder: 2-layer GCN on MI355X (gfx950).
// Pipeline: hist -> scan(3) -> dinv -> fill CSR -> [gemm+scale(bf16 out) -> aggregate] x2
// R4 fix: GEMM kc loop ROLLED (barrier-bounded scheduling window), k4 unroll 2.
// R1's fully-unrolled 32-step K-loop spilled (VGPR=256, 6.3 GB scratch traffic, 3.6 ms).

typedef unsigned int uint;

// ---------- bf16 helpers (bit-level, RNE pack) ----------
__device__ __forceinline__ float bf_lo(uint v) { return __uint_as_float(v << 16); }
__device__ __forceinline__ float bf_hi(uint v) { return __uint_as_float(v & 0xffff0000u); }
__device__ __forceinline__ uint pack_bf16(float x, float y) {
    uint bx = __float_as_uint(x), by = __float_as_uint(y);
    bx += 0x7fffu + ((bx >> 16) & 1u);
    by += 0x7fffu + ((by >> 16) & 1u);
    return (bx >> 16) | (by & 0xffff0000u);
}

// ---------------- CSR build ----------------

__global__ __launch_bounds__(256) void hist_kernel(const int4* __restrict__ col4,
                                                   int* __restrict__ counts, int E4) {
    int i = blockIdx.x * 256 + threadIdx.x;
    if (i < E4) {
        int4 c = col4[i];
        atomicAdd(&counts[c.x], 1);
        atomicAdd(&counts[c.y], 1);
        atomicAdd(&counts[c.z], 1);
        atomicAdd(&counts[c.w], 1);
    }
}

// exclusive scan, phase A: per-block (1024 elems) Hillis-Steele
__global__ __launch_bounds__(1024) void scan_a(const int* __restrict__ counts,
                                               int* __restrict__ rp,
                                               int* __restrict__ bsums, int n) {
    __shared__ int s[2][1024];
    int t = threadIdx.x;
    int i = blockIdx.x * 1024 + t;
    int v = (i < n) ? counts[i] : 0;
    s[0][t] = v;
    __syncthreads();
    int p = 0;
    for (int d = 1; d < 1024; d <<= 1) {
        int val = s[p][t] + ((t >= d) ? s[p][t - d] : 0);
        s[p ^ 1][t] = val;
        p ^= 1;
        __syncthreads();
    }
    if (i < n) rp[i] = s[p][t] - v;
    if (t == 1023) bsums[blockIdx.x] = s[p][t];
}

__global__ __launch_bounds__(128) void scan_b(int* __restrict__ bsums, int nb) {
    __shared__ int s[2][128];
    int t = threadIdx.x;
    int v = (t < nb) ? bsums[t] : 0;
    s[0][t] = v;
    __syncthreads();
    int p = 0;
    for (int d = 1; d < 128; d <<= 1) {
        int val = s[p][t] + ((t >= d) ? s[p][t - d] : 0);
        s[p ^ 1][t] = val;
        p ^= 1;
        __syncthreads();
    }
    if (t < nb) bsums[t] = s[p][t] - v;
}

__global__ __launch_bounds__(256) void scan_c(int* __restrict__ rp,
                                              const int* __restrict__ bsums, int n, int E) {
    int i = blockIdx.x * 256 + threadIdx.x;
    if (i < n)       rp[i] += bsums[i >> 10];
    else if (i == n) rp[n] = E;
}

__global__ __launch_bounds__(256) void dinv_kernel(const int* __restrict__ counts,
                                                   float* __restrict__ dinv, int n) {
    int i = blockIdx.x * 256 + threadIdx.x;
    if (i < n) dinv[i] = rsqrtf((float)(counts[i] + 1)); // +1 = self loop
}

__global__ __launch_bounds__(256) void fill_kernel(const int* __restrict__ row,
                                                   const int* __restrict__ col,
                                                   const int* __restrict__ rp,
                                                   int* __restrict__ fill,
                                                   int* __restrict__ csr, int E) {
    int i = blockIdx.x * 256 + threadIdx.x;
    if (i < E) {
        int c = col[i];
        int p = rp[c] + atomicAdd(&fill[c], 1);
        csr[p] = row[i];
    }
}

// ---------------- GEMM: out[m][n] = bf16( dinv[m] * sum_k X[m][k] * W[k][n] ) ----------------
// K=128. f32 VALU (no fp32 MFMA). X tile 64x(128+pad) in LDS; W staged in 32-k chunks in LDS.
// kc loop ROLLED so barriers bound the scheduler's load-hoisting window (anti-spill).

template <int NC, bool BF16_IN>
__global__ __launch_bounds__(256) void gemm_scale(const void* __restrict__ Xv,
                                                  const float* __restrict__ W,
                                                  const float* __restrict__ dinv,
                                                  uint* __restrict__ out, int M) {
    constexpr int K = 128, BM = 64, PAD = 132, CPT = NC / 16;
    __shared__ float xs[BM * PAD];
    __shared__ float ws[32 * NC];

    int tid = threadIdx.x;
    int block_row = blockIdx.x * BM;

    // stage X tile
    if (BF16_IN) {
        const uint* X = (const uint*)Xv;          // row = 64 uints (128 bf16)
        int r = tid >> 5, c = tid & 31;           // c -> bf16 cols c*4..c*4+3
#pragma unroll
        for (int p = 0; p < 8; ++p) {
            int rr = r + p * 8;
            int gr = block_row + rr;
            if (gr > M - 1) gr = M - 1;
            uint2 v = *(const uint2*)(X + (size_t)gr * 64 + c * 2);
            float* d = xs + rr * PAD + c * 4;
            d[0] = bf_lo(v.x); d[1] = bf_hi(v.x);
            d[2] = bf_lo(v.y); d[3] = bf_hi(v.y);
        }
    } else {
        const float* X = (const float*)Xv;
        int r = tid >> 5, k4 = tid & 31;
#pragma unroll
        for (int p = 0; p < 8; ++p) {
            int rr = r + p * 8;
            int gr = block_row + rr;
            if (gr > M - 1) gr = M - 1;
            float4 v = *(const float4*)(X + (size_t)gr * K + k4 * 4);
            *(float4*)(xs + rr * PAD + k4 * 4) = v;
        }
    }

    int tc = tid & 15;   // col group
    int tr = tid >> 4;   // row group (0..15), 4 rows each

    float acc[4][CPT];
#pragma unroll
    for (int i = 0; i < 4; ++i)
#pragma unroll
        for (int j = 0; j < CPT; ++j) acc[i][j] = 0.0f;

    for (int kc = 0; kc < K / 32; ++kc) {   // ROLLED: barrier bounds sched window
        // stage W chunk [32][NC]
        {
            const float4* src = (const float4*)(W + (size_t)kc * 32 * NC);
            float4* dst = (float4*)ws;
#pragma unroll
            for (int i = 0; i < NC / 32; ++i) dst[tid + i * 256] = src[tid + i * 256];
        }
        __syncthreads();

#pragma unroll 2
        for (int k4 = 0; k4 < 8; ++k4) {
            float4 xa[4];
#pragma unroll
            for (int i = 0; i < 4; ++i)
                xa[i] = *(const float4*)(xs + (tr * 4 + i) * PAD + kc * 32 + k4 * 4);
#pragma unroll
            for (int kk = 0; kk < 4; ++kk) {
                float wv[CPT];
#pragma unroll
                for (int m = 0; m < CPT / 4; ++m) {
                    float4 w4 = *(const float4*)(ws + (k4 * 4 + kk) * NC + tc * CPT + m * 4);
                    wv[m * 4 + 0] = w4.x; wv[m * 4 + 1] = w4.y;
                    wv[m * 4 + 2] = w4.z; wv[m * 4 + 3] = w4.w;
                }
#pragma unroll
                for (int i = 0; i < 4; ++i) {
                    float xv = (&xa[i].x)[kk];
#pragma unroll
                    for (int j = 0; j < CPT; ++j) acc[i][j] = fmaf(xv, wv[j], acc[i][j]);
                }
            }
        }
        __syncthreads();
    }

    // epilogue: scale by dinv, pack bf16 pairs, direct vector store (no local array)
#pragma unroll
    for (int i = 0; i < 4; ++i) {
        int r = block_row + tr * 4 + i;
        if (r < M) {
            float di = dinv[r];
            if (CPT == 8) {
                uint4 o;
                o.x = pack_bf16(acc[i][0] * di, acc[i][1] * di);
                o.y = pack_bf16(acc[i][2] * di, acc[i][3] * di);
                o.z = pack_bf16(acc[i][4] * di, acc[i][5] * di);
                o.w = pack_bf16(acc[i][6] * di, acc[i][7] * di);
                *(uint4*)(out + (size_t)r * 64 + tc * 4) = o;
            } else {
                uint2 o;
                o.x = pack_bf16(acc[i][0] * di, acc[i][1] * di);
                o.y = pack_bf16(acc[i][2] * di, acc[i][3] * di);
                *(uint2*)(out + (size_t)r * 32 + tc * 2) = o;
            }
        }
    }
}

// ---------------- Aggregation ----------------
// layer1: h[c] = bf16( relu(dinv[c]*(xws[c] + sum_src xws[src]) + b) ), 128 cols (64 uints), wave/node
// 4 gathers in flight per wave.

__global__ __launch_bounds__(256) void agg128(const uint* __restrict__ xws,
                                              const int* __restrict__ rp,
                                              const int* __restrict__ csr,
                                              const float* __restrict__ dinv,
                                              const float* __restrict__ bias,
                                              uint* __restrict__ h, int n) {
    int gid  = blockIdx.x * 256 + threadIdx.x;
    int node = gid >> 6;
    int lane = gid & 63;
    if (node >= n) return;

    uint self = xws[(size_t)node * 64 + lane];
    float ax = bf_lo(self), ay = bf_hi(self);

    int beg = rp[node], end = rp[node + 1];
    int e = beg;
    for (; e + 4 <= end; e += 4) {
        int s0 = csr[e], s1 = csr[e + 1], s2 = csr[e + 2], s3 = csr[e + 3];
        uint v0 = xws[(size_t)s0 * 64 + lane];
        uint v1 = xws[(size_t)s1 * 64 + lane];
        uint v2 = xws[(size_t)s2 * 64 + lane];
        uint v3 = xws[(size_t)s3 * 64 + lane];
        ax += bf_lo(v0) + bf_lo(v1) + bf_lo(v2) + bf_lo(v3);
        ay += bf_hi(v0) + bf_hi(v1) + bf_hi(v2) + bf_hi(v3);
    }
    for (; e < end; ++e) {
        uint v = xws[(size_t)csr[e] * 64 + lane];
        ax += bf_lo(v);
        ay += bf_hi(v);
    }

    float  di = dinv[node];
    float2 b  = ((const float2*)bias)[lane];
    float ox = fmaxf(fmaf(di, ax, b.x), 0.0f);
    float oy = fmaxf(fmaf(di, ay, b.y), 0.0f);
    h[(size_t)node * 64 + lane] = pack_bf16(ox, oy);
}

// layer2: out = dinv*(self + sum) + b, 64 cols (32 uints), half-wave per node, f32 output.

__global__ __launch_bounds__(256) void agg64(const uint* __restrict__ xws,
                                             const int* __restrict__ rp,
                                             const int* __restrict__ csr,
                                             const float* __restrict__ dinv,
                                             const float* __restrict__ bias,
                                             float* __restrict__ out, int n) {
    int gid  = blockIdx.x * 256 + threadIdx.x;
    int node = gid >> 5;
    int l    = gid & 31;
    if (node >= n) return;

    uint self = xws[(size_t)node * 32 + l];
    float ax = bf_lo(self), ay = bf_hi(self);

    int beg = rp[node], end = rp[node + 1];
    int e = beg;
    for (; e + 4 <= end; e += 4) {
        int s0 = csr[e], s1 = csr[e + 1], s2 = csr[e + 2], s3 = csr[e + 3];
        uint v0 = xws[(size_t)s0 * 32 + l];
        uint v1 = xws[(size_t)s1 * 32 + l];
        uint v2 = xws[(size_t)s2 * 32 + l];
        uint v3 = xws[(size_t)s3 * 32 + l];
        ax += bf_lo(v0) + bf_lo(v1) + bf_lo(v2) + bf_lo(v3);
        ay += bf_hi(v0) + bf_hi(v1) + bf_hi(v2) + bf_hi(v3);
    }
    for (; e < end; ++e) {
        uint v = xws[(size_t)csr[e] * 32 + l];
        ax += bf_lo(v);
        ay += bf_hi(v);
    }

    float  di = dinv[node];
    float2 b  = ((const float2*)bias)[l];
    float2 o;
    o.x = fmaf(di, ax, b.x);
    o.y = fmaf(di, ay, b.y);
    ((float2*)out)[(size_t)node * 32 + l] = o;
}

// ---------------- launch ----------------

static inline size_t align512(size_t x) { return (x + 511) & ~(size_t)511; }

extern "C" void kernel_launch(void* const* d_in, const int* in_sizes, int n_in,
                              void* d_out, int out_size, void* d_ws, size_t ws_size,
                              hipStream_t stream) {
    const float* x   = (const float*)d_in[0];
    const int*   ei  = (const int*)d_in[1];
    const float* W1  = (const float*)d_in[2];
    const float* b1  = (const float*)d_in[3];
    const float* W2  = (const float*)d_in[4];
    const float* b2  = (const float*)d_in[5];
    float*       out = (float*)d_out;

    const int N = in_sizes[0] / 128;   // 100000
    const int E = in_sizes[1] / 2;     // 1600000
    const int* row = ei;
    const int* col = ei + E;

    // workspace carve-up
    char* w = (char*)d_ws;
    size_t off = 0;
    auto take = [&](size_t bytes) { void* p = w + off; off = align512(off + bytes); return p; };
    int*   counts = (int*)  take((size_t)N * 4);
    int*   fill   = (int*)  take((size_t)N * 4);
    size_t zero_bytes = off;                     // counts + fill must start at 0
    int*   rp     = (int*)  take((size_t)(N + 1) * 4);
    int*   bsums  = (int*)  take(512);
    float* dinv   = (float*)take((size_t)N * 4);
    int*   csr    = (int*)  take((size_t)E * 4);
    uint*  xws    = (uint*) take((size_t)N * 64 * 4);   // bf16-packed [N,128] (layer1) / reused [N,64] (layer2)
    uint*  h      = (uint*) take((size_t)N * 64 * 4);   // bf16-packed [N,128]
    (void)ws_size;

    hipMemsetAsync(d_ws, 0, zero_bytes, stream);

    const int nb = (N + 1023) / 1024;

    hist_kernel<<<(E / 4 + 255) / 256, 256, 0, stream>>>((const int4*)col, counts, E / 4);
    scan_a<<<nb, 1024, 0, stream>>>(counts, rp, bsums, N);
    scan_b<<<1, 128, 0, stream>>>(bsums, nb);
    scan_c<<<(N + 256) / 256, 256, 0, stream>>>(rp, bsums, N, E);
    dinv_kernel<<<(N + 255) / 256, 256, 0, stream>>>(counts, dinv, N);
    fill_kernel<<<(E + 255) / 256, 256, 0, stream>>>(row, col, rp, fill, csr, E);

    // layer 1
    gemm_scale<128, false><<<(N + 63) / 64, 256, 0, stream>>>(x, W1, dinv, xws, N);
    agg128<<<(N + 3) / 4, 256, 0, stream>>>(xws, rp, csr, dinv, b1, h, N);

    // layer 2
    gemm_scale<64, true><<<(N + 63) / 64, 256, 0, stream>>>(h, W2, dinv, xws, N);
    agg64<<<(N + 7) / 8, 256, 0, stream>>>(xws, rp, csr, dinv, b2, out, N);
}

// Round 6
// 417.783 us; speedup vs baseline: 11.1254x; 1.1366x over previous
//
#include <hip/hip_runtime.h>

// GAE encoder: 2-layer GCN on MI355X (gfx950).
// R6: CSR build via bucket partition (kills 64B-line write-amplification of the
// atomic scatter fill: WRITE_SIZE was 107MB for a 6.4MB csr -> one-block-per-line ownership).
// Pipeline: hist -> scan(rp) -> dinv -> bucket_hist -> scan(loff) -> partition -> fill2
//           -> [gemm+scale(bf16 out) -> aggregate] x2

typedef unsigned int uint;

#define BKT_SH 7               // 128 cols per bucket
#define NBUCK_MAX 1024
#define CHUNK 8192             // edges per partition block

// ---------- bf16 helpers (bit-level, RNE pack) ----------
__device__ __forceinline__ float bf_lo(uint v) { return __uint_as_float(v << 16); }
__device__ __forceinline__ float bf_hi(uint v) { return __uint_as_float(v & 0xffff0000u); }
__device__ __forceinline__ uint pack_bf16(float x, float y) {
    uint bx = __float_as_uint(x), by = __float_as_uint(y);
    bx += 0x7fffu + ((bx >> 16) & 1u);
    by += 0x7fffu + ((by >> 16) & 1u);
    return (bx >> 16) | (by & 0xffff0000u);
}

// ---------------- degree histogram ----------------

__global__ __launch_bounds__(256) void hist_kernel(const int4* __restrict__ col4,
                                                   int* __restrict__ counts, int E4) {
    int i = blockIdx.x * 256 + threadIdx.x;
    if (i < E4) {
        int4 c = col4[i];
        atomicAdd(&counts[c.x], 1);
        atomicAdd(&counts[c.y], 1);
        atomicAdd(&counts[c.z], 1);
        atomicAdd(&counts[c.w], 1);
    }
}

// ---------------- generic exclusive scan (A: per-1024 block, B: <=256 sums, C: add) ----

__global__ __launch_bounds__(1024) void scan_a(const int* __restrict__ in,
                                               int* __restrict__ outp,
                                               int* __restrict__ bsums, int n) {
    __shared__ int s[2][1024];
    int t = threadIdx.x;
    int i = blockIdx.x * 1024 + t;
    int v = (i < n) ? in[i] : 0;
    s[0][t] = v;
    __syncthreads();
    int p = 0;
    for (int d = 1; d < 1024; d <<= 1) {
        int val = s[p][t] + ((t >= d) ? s[p][t - d] : 0);
        s[p ^ 1][t] = val;
        p ^= 1;
        __syncthreads();
    }
    if (i < n) outp[i] = s[p][t] - v;
    if (t == 1023) bsums[blockIdx.x] = s[p][t];
}

__global__ __launch_bounds__(256) void scan_b(int* __restrict__ bsums, int nb) {
    __shared__ int s[2][256];
    int t = threadIdx.x;
    int v = (t < nb) ? bsums[t] : 0;
    s[0][t] = v;
    __syncthreads();
    int p = 0;
    for (int d = 1; d < 256; d <<= 1) {
        int val = s[p][t] + ((t >= d) ? s[p][t - d] : 0);
        s[p ^ 1][t] = val;
        p ^= 1;
        __syncthreads();
    }
    if (t < nb) bsums[t] = s[p][t] - v;
}

__global__ __launch_bounds__(256) void scan_c(int* __restrict__ outp,
                                              const int* __restrict__ bsums, int n, int total) {
    int i = blockIdx.x * 256 + threadIdx.x;
    if (i < n)       outp[i] += bsums[i >> 10];
    else if (i == n) outp[n] = total;
}

__global__ __launch_bounds__(256) void dinv_kernel(const int* __restrict__ counts,
                                                   float* __restrict__ dinv, int n) {
    int i = blockIdx.x * 256 + threadIdx.x;
    if (i < n) dinv[i] = rsqrtf((float)(counts[i] + 1)); // +1 = self loop
}

// ---------------- bucket partition CSR build ----------------
// pass 1a: per-(bucket, block) histogram. lhist[bucket*nblk + blk].

__global__ __launch_bounds__(256) void bucket_hist(const int* __restrict__ col,
                                                   int* __restrict__ lhist,
                                                   int E, int nbuck, int nblk) {
    __shared__ int sh[NBUCK_MAX];
    int t = threadIdx.x;
    for (int b = t; b < nbuck; b += 256) sh[b] = 0;
    __syncthreads();
    const int4* c4 = (const int4*)col;
    int i4base = blockIdx.x * (CHUNK / 4);
    int E4 = E >> 2;
#pragma unroll
    for (int it = 0; it < CHUNK / 4 / 256; ++it) {
        int i4 = i4base + it * 256 + t;
        if (i4 < E4) {
            int4 c = c4[i4];
            atomicAdd(&sh[c.x >> BKT_SH], 1);
            atomicAdd(&sh[c.y >> BKT_SH], 1);
            atomicAdd(&sh[c.z >> BKT_SH], 1);
            atomicAdd(&sh[c.w >> BKT_SH], 1);
        }
    }
    // scalar tail (E not multiple of 4), handled by block 0
    if (blockIdx.x == 0 && t < (E & 3)) atomicAdd(&sh[col[(E & ~3) + t] >> BKT_SH], 1);
    __syncthreads();
    for (int b = t; b < nbuck; b += 256) lhist[b * nblk + blockIdx.x] = sh[b];
}

// pass 1b: write (col,row) pairs into per-(bucket,block) contiguous runs.

__global__ __launch_bounds__(256) void partition_kernel(const int* __restrict__ row,
                                                        const int* __restrict__ col,
                                                        const int* __restrict__ loff,
                                                        uint2* __restrict__ part,
                                                        int E, int nbuck, int nblk) {
    __shared__ int cur[NBUCK_MAX];
    int t = threadIdx.x;
    for (int b = t; b < nbuck; b += 256) cur[b] = loff[b * nblk + blockIdx.x];
    __syncthreads();
    const int4* c4 = (const int4*)col;
    const int4* r4 = (const int4*)row;
    int i4base = blockIdx.x * (CHUNK / 4);
    int E4 = E >> 2;
#pragma unroll
    for (int it = 0; it < CHUNK / 4 / 256; ++it) {
        int i4 = i4base + it * 256 + t;
        if (i4 < E4) {
            int4 c = c4[i4];
            int4 r = r4[i4];
            int p0 = atomicAdd(&cur[c.x >> BKT_SH], 1); part[p0] = make_uint2((uint)c.x, (uint)r.x);
            int p1 = atomicAdd(&cur[c.y >> BKT_SH], 1); part[p1] = make_uint2((uint)c.y, (uint)r.y);
            int p2 = atomicAdd(&cur[c.z >> BKT_SH], 1); part[p2] = make_uint2((uint)c.z, (uint)r.z);
            int p3 = atomicAdd(&cur[c.w >> BKT_SH], 1); part[p3] = make_uint2((uint)c.w, (uint)r.w);
        }
    }
    if (blockIdx.x == 0 && t < (E & 3)) {
        int e = (E & ~3) + t;
        int c = col[e];
        int p = atomicAdd(&cur[c >> BKT_SH], 1);
        part[p] = make_uint2((uint)c, (uint)row[e]);
    }
}

// pass 2: one block per bucket; LDS per-col cursors; csr writes confined to ~8KB window.

__global__ __launch_bounds__(256) void fill2(const uint2* __restrict__ part,
                                             const int* __restrict__ loff,
                                             const int* __restrict__ rp,
                                             int* __restrict__ csr,
                                             int E, int nbuck, int nblk, int N) {
    __shared__ int lcur[1 << BKT_SH];
    __shared__ int lbase[1 << BKT_SH];
    int b = blockIdx.x;
    int t = threadIdx.x;
    if (t < (1 << BKT_SH)) {
        lcur[t] = 0;
        int c = (b << BKT_SH) + t;
        lbase[t] = (c < N) ? rp[c] : 0;
    }
    __syncthreads();
    int beg = loff[b * nblk];
    int end = (b + 1 < nbuck) ? loff[(b + 1) * nblk] : E;
    for (int e = beg + t; e < end; e += 256) {
        uint2 pr = part[e];
        int cl = (int)pr.x & ((1 << BKT_SH) - 1);
        int slot = atomicAdd(&lcur[cl], 1);
        csr[lbase[cl] + slot] = (int)pr.y;
    }
}

// ---------------- GEMM: out[m][n] = bf16( dinv[m] * sum_k X[m][k] * W[k][n] ) ----------------
// K=128. f32 VALU. X tile 64x(128+pad) in LDS; W staged in 32-k chunks in LDS.
// kc loop ROLLED so barriers bound the scheduler's load-hoisting window (anti-spill).

template <int NC, bool BF16_IN>
__global__ __launch_bounds__(256) void gemm_scale(const void* __restrict__ Xv,
                                                  const float* __restrict__ W,
                                                  const float* __restrict__ dinv,
                                                  uint* __restrict__ out, int M) {
    constexpr int K = 128, BM = 64, PAD = 132, CPT = NC / 16;
    __shared__ float xs[BM * PAD];
    __shared__ float ws[32 * NC];

    int tid = threadIdx.x;
    int block_row = blockIdx.x * BM;

    // stage X tile
    if (BF16_IN) {
        const uint* X = (const uint*)Xv;          // row = 64 uints (128 bf16)
        int r = tid >> 5, c = tid & 31;
#pragma unroll
        for (int p = 0; p < 8; ++p) {
            int rr = r + p * 8;
            int gr = block_row + rr;
            if (gr > M - 1) gr = M - 1;
            uint2 v = *(const uint2*)(X + (size_t)gr * 64 + c * 2);
            float* d = xs + rr * PAD + c * 4;
            d[0] = bf_lo(v.x); d[1] = bf_hi(v.x);
            d[2] = bf_lo(v.y); d[3] = bf_hi(v.y);
        }
    } else {
        const float* X = (const float*)Xv;
        int r = tid >> 5, k4 = tid & 31;
#pragma unroll
        for (int p = 0; p < 8; ++p) {
            int rr = r + p * 8;
            int gr = block_row + rr;
            if (gr > M - 1) gr = M - 1;
            float4 v = *(const float4*)(X + (size_t)gr * K + k4 * 4);
            *(float4*)(xs + rr * PAD + k4 * 4) = v;
        }
    }

    int tc = tid & 15;   // col group
    int tr = tid >> 4;   // row group (0..15), 4 rows each

    float acc[4][CPT];
#pragma unroll
    for (int i = 0; i < 4; ++i)
#pragma unroll
        for (int j = 0; j < CPT; ++j) acc[i][j] = 0.0f;

    for (int kc = 0; kc < K / 32; ++kc) {   // ROLLED: barrier bounds sched window
        {
            const float4* src = (const float4*)(W + (size_t)kc * 32 * NC);
            float4* dst = (float4*)ws;
#pragma unroll
            for (int i = 0; i < NC / 32; ++i) dst[tid + i * 256] = src[tid + i * 256];
        }
        __syncthreads();

#pragma unroll 2
        for (int k4 = 0; k4 < 8; ++k4) {
            float4 xa[4];
#pragma unroll
            for (int i = 0; i < 4; ++i)
                xa[i] = *(const float4*)(xs + (tr * 4 + i) * PAD + kc * 32 + k4 * 4);
#pragma unroll
            for (int kk = 0; kk < 4; ++kk) {
                float wv[CPT];
#pragma unroll
                for (int m = 0; m < CPT / 4; ++m) {
                    float4 w4 = *(const float4*)(ws + (k4 * 4 + kk) * NC + tc * CPT + m * 4);
                    wv[m * 4 + 0] = w4.x; wv[m * 4 + 1] = w4.y;
                    wv[m * 4 + 2] = w4.z; wv[m * 4 + 3] = w4.w;
                }
#pragma unroll
                for (int i = 0; i < 4; ++i) {
                    float xv = (&xa[i].x)[kk];
#pragma unroll
                    for (int j = 0; j < CPT; ++j) acc[i][j] = fmaf(xv, wv[j], acc[i][j]);
                }
            }
        }
        __syncthreads();
    }

#pragma unroll
    for (int i = 0; i < 4; ++i) {
        int r = block_row + tr * 4 + i;
        if (r < M) {
            float di = dinv[r];
            if (CPT == 8) {
                uint4 o;
                o.x = pack_bf16(acc[i][0] * di, acc[i][1] * di);
                o.y = pack_bf16(acc[i][2] * di, acc[i][3] * di);
                o.z = pack_bf16(acc[i][4] * di, acc[i][5] * di);
                o.w = pack_bf16(acc[i][6] * di, acc[i][7] * di);
                *(uint4*)(out + (size_t)r * 64 + tc * 4) = o;
            } else {
                uint2 o;
                o.x = pack_bf16(acc[i][0] * di, acc[i][1] * di);
                o.y = pack_bf16(acc[i][2] * di, acc[i][3] * di);
                *(uint2*)(out + (size_t)r * 32 + tc * 2) = o;
            }
        }
    }
}

// ---------------- Aggregation ----------------

__global__ __launch_bounds__(256) void agg128(const uint* __restrict__ xws,
                                              const int* __restrict__ rp,
                                              const int* __restrict__ csr,
                                              const float* __restrict__ dinv,
                                              const float* __restrict__ bias,
                                              uint* __restrict__ h, int n) {
    int gid  = blockIdx.x * 256 + threadIdx.x;
    int node = gid >> 6;
    int lane = gid & 63;
    if (node >= n) return;

    uint self = xws[(size_t)node * 64 + lane];
    float ax = bf_lo(self), ay = bf_hi(self);

    int beg = rp[node], end = rp[node + 1];
    int e = beg;
    for (; e + 4 <= end; e += 4) {
        int s0 = csr[e], s1 = csr[e + 1], s2 = csr[e + 2], s3 = csr[e + 3];
        uint v0 = xws[(size_t)s0 * 64 + lane];
        uint v1 = xws[(size_t)s1 * 64 + lane];
        uint v2 = xws[(size_t)s2 * 64 + lane];
        uint v3 = xws[(size_t)s3 * 64 + lane];
        ax += bf_lo(v0) + bf_lo(v1) + bf_lo(v2) + bf_lo(v3);
        ay += bf_hi(v0) + bf_hi(v1) + bf_hi(v2) + bf_hi(v3);
    }
    for (; e < end; ++e) {
        uint v = xws[(size_t)csr[e] * 64 + lane];
        ax += bf_lo(v);
        ay += bf_hi(v);
    }

    float  di = dinv[node];
    float2 b  = ((const float2*)bias)[lane];
    float ox = fmaxf(fmaf(di, ax, b.x), 0.0f);
    float oy = fmaxf(fmaf(di, ay, b.y), 0.0f);
    h[(size_t)node * 64 + lane] = pack_bf16(ox, oy);
}

__global__ __launch_bounds__(256) void agg64(const uint* __restrict__ xws,
                                             const int* __restrict__ rp,
                                             const int* __restrict__ csr,
                                             const float* __restrict__ dinv,
                                             const float* __restrict__ bias,
                                             float* __restrict__ out, int n) {
    int gid  = blockIdx.x * 256 + threadIdx.x;
    int node = gid >> 5;
    int l    = gid & 31;
    if (node >= n) return;

    uint self = xws[(size_t)node * 32 + l];
    float ax = bf_lo(self), ay = bf_hi(self);

    int beg = rp[node], end = rp[node + 1];
    int e = beg;
    for (; e + 4 <= end; e += 4) {
        int s0 = csr[e], s1 = csr[e + 1], s2 = csr[e + 2], s3 = csr[e + 3];
        uint v0 = xws[(size_t)s0 * 32 + l];
        uint v1 = xws[(size_t)s1 * 32 + l];
        uint v2 = xws[(size_t)s2 * 32 + l];
        uint v3 = xws[(size_t)s3 * 32 + l];
        ax += bf_lo(v0) + bf_lo(v1) + bf_lo(v2) + bf_lo(v3);
        ay += bf_hi(v0) + bf_hi(v1) + bf_hi(v2) + bf_hi(v3);
    }
    for (; e < end; ++e) {
        uint v = xws[(size_t)csr[e] * 32 + l];
        ax += bf_lo(v);
        ay += bf_hi(v);
    }

    float  di = dinv[node];
    float2 b  = ((const float2*)bias)[l];
    float2 o;
    o.x = fmaf(di, ax, b.x);
    o.y = fmaf(di, ay, b.y);
    ((float2*)out)[(size_t)node * 32 + l] = o;
}

// ---------------- launch ----------------

static inline size_t align512(size_t x) { return (x + 511) & ~(size_t)511; }

extern "C" void kernel_launch(void* const* d_in, const int* in_sizes, int n_in,
                              void* d_out, int out_size, void* d_ws, size_t ws_size,
                              hipStream_t stream) {
    const float* x   = (const float*)d_in[0];
    const int*   ei  = (const int*)d_in[1];
    const float* W1  = (const float*)d_in[2];
    const float* b1  = (const float*)d_in[3];
    const float* W2  = (const float*)d_in[4];
    const float* b2  = (const float*)d_in[5];
    float*       out = (float*)d_out;

    const int N = in_sizes[0] / 128;   // 100000
    const int E = in_sizes[1] / 2;     // 1600000
    const int* row = ei;
    const int* col = ei + E;

    const int nbuck = (N + (1 << BKT_SH) - 1) >> BKT_SH;     // 782
    const int nblk  = (E + CHUNK - 1) / CHUNK;               // 196
    const int L     = nbuck * nblk;                          // lhist elements

    // workspace carve-up
    char* w = (char*)d_ws;
    size_t off = 0;
    auto take = [&](size_t bytes) { void* p = w + off; off = align512(off + bytes); return p; };
    int*   counts = (int*)  take((size_t)N * 4);
    size_t zero_bytes = off;                     // counts must start at 0
    int*   rp     = (int*)  take((size_t)(N + 1) * 4);
    int*   bsums  = (int*)  take(4096);
    float* dinv   = (float*)take((size_t)N * 4);
    int*   csr    = (int*)  take((size_t)E * 4);
    uint*  xws    = (uint*) take((size_t)N * 64 * 4);   // bf16-packed [N,128] / [N,64]
    uint*  h      = (uint*) take((size_t)N * 64 * 4);   // bf16-packed [N,128]
    (void)ws_size;
    // CSR-build temporaries alias the (not-yet-live) xws / h buffers:
    int*   lhist = (int*)xws;                 // L ints
    int*   loff  = (int*)xws + L + 128;       // L+1 ints (xws = 25.6MB >> 2*L*4)
    uint2* part  = (uint2*)h;                 // E pairs (12.8MB <= 25.6MB)

    hipMemsetAsync(d_ws, 0, zero_bytes, stream);

    // degree -> rp, dinv
    hist_kernel<<<(E / 4 + 255) / 256, 256, 0, stream>>>((const int4*)col, counts, E / 4);
    int nb1 = (N + 1023) / 1024;
    scan_a<<<nb1, 1024, 0, stream>>>(counts, rp, bsums, N);
    scan_b<<<1, 256, 0, stream>>>(bsums, nb1);
    scan_c<<<(N + 256) / 256, 256, 0, stream>>>(rp, bsums, N, E);
    dinv_kernel<<<(N + 255) / 256, 256, 0, stream>>>(counts, dinv, N);

    // bucket partition -> csr
    bucket_hist<<<nblk, 256, 0, stream>>>(col, lhist, E, nbuck, nblk);
    int nb2 = (L + 1023) / 1024;
    scan_a<<<nb2, 1024, 0, stream>>>(lhist, loff, bsums, L);
    scan_b<<<1, 256, 0, stream>>>(bsums, nb2);
    scan_c<<<(L + 256) / 256, 256, 0, stream>>>(loff, bsums, L, E);
    partition_kernel<<<nblk, 256, 0, stream>>>(row, col, loff, part, E, nbuck, nblk);
    fill2<<<nbuck, 256, 0, stream>>>(part, loff, rp, csr, E, nbuck, nblk, N);

    // layer 1
    gemm_scale<128, false><<<(N + 63) / 64, 256, 0, stream>>>(x, W1, dinv, xws, N);
    agg128<<<(N + 3) / 4, 256, 0, stream>>>(xws, rp, csr, dinv, b1, h, N);

    // layer 2
    gemm_scale<64, true><<<(N + 63) / 64, 256, 0, stream>>>(h, W2, dinv, xws, N);
    agg64<<<(N + 7) / 8, 256, 0, stream>>>(xws, rp, csr, dinv, b2, out, N);
}

// Round 8
// 332.325 us; speedup vs baseline: 13.9863x; 1.2572x over previous
//
#include <hip/hip_runtime.h>

// GAE encoder: 2-layer GCN on MI355X (gfx950).
// R7: CSR build collapsed to 6 kernels: bucket_hist -> scan(loff) x3 -> partition -> fill2.
//     fill2 derives rp + dinv itself (bucket-major flat scan => loff[b*nblk] == rp[b*128]).
//     agg kernels: 8-deep gather unroll (latency-bound at VALUBusy 34% with 4-deep).
// Pipeline: bucket_hist -> scan -> partition -> fill2(rp,dinv,csr) -> [gemm -> agg] x2

typedef unsigned int uint;

#define BKT_SH 7               // 128 cols per bucket
#define BKT    (1 << BKT_SH)
#define NBUCK_MAX 1024
#define CHUNK 16384            // edges per partition block

// ---------- bf16 helpers (bit-level, RNE pack) ----------
__device__ __forceinline__ float bf_lo(uint v) { return __uint_as_float(v << 16); }
__device__ __forceinline__ float bf_hi(uint v) { return __uint_as_float(v & 0xffff0000u); }
__device__ __forceinline__ uint pack_bf16(float x, float y) {
    uint bx = __float_as_uint(x), by = __float_as_uint(y);
    bx += 0x7fffu + ((bx >> 16) & 1u);
    by += 0x7fffu + ((by >> 16) & 1u);
    return (bx >> 16) | (by & 0xffff0000u);
}

// ---------------- generic exclusive scan (A: per-1024 block, B: <=256 sums, C: add) ----

__global__ __launch_bounds__(1024) void scan_a(const int* __restrict__ in,
                                               int* __restrict__ outp,
                                               int* __restrict__ bsums, int n) {
    __shared__ int s[2][1024];
    int t = threadIdx.x;
    int i = blockIdx.x * 1024 + t;
    int v = (i < n) ? in[i] : 0;
    s[0][t] = v;
    __syncthreads();
    int p = 0;
    for (int d = 1; d < 1024; d <<= 1) {
        int val = s[p][t] + ((t >= d) ? s[p][t - d] : 0);
        s[p ^ 1][t] = val;
        p ^= 1;
        __syncthreads();
    }
    if (i < n) outp[i] = s[p][t] - v;
    if (t == 1023) bsums[blockIdx.x] = s[p][t];
}

__global__ __launch_bounds__(256) void scan_b(int* __restrict__ bsums, int nb) {
    __shared__ int s[2][256];
    int t = threadIdx.x;
    int v = (t < nb) ? bsums[t] : 0;
    s[0][t] = v;
    __syncthreads();
    int p = 0;
    for (int d = 1; d < 256; d <<= 1) {
        int val = s[p][t] + ((t >= d) ? s[p][t - d] : 0);
        s[p ^ 1][t] = val;
        p ^= 1;
        __syncthreads();
    }
    if (t < nb) bsums[t] = s[p][t] - v;
}

__global__ __launch_bounds__(256) void scan_c(int* __restrict__ outp,
                                              const int* __restrict__ bsums, int n, int total) {
    int i = blockIdx.x * 256 + threadIdx.x;
    if (i < n)       outp[i] += bsums[i >> 10];
    else if (i == n) outp[n] = total;
}

// ---------------- bucket partition CSR build ----------------
// pass 1a: per-(bucket, block) histogram. lhist[bucket*nblk + blk].

__global__ __launch_bounds__(256) void bucket_hist(const int* __restrict__ col,
                                                   int* __restrict__ lhist,
                                                   int E, int nbuck, int nblk) {
    __shared__ int sh[NBUCK_MAX];
    int t = threadIdx.x;
    for (int b = t; b < nbuck; b += 256) sh[b] = 0;
    __syncthreads();
    const int4* c4 = (const int4*)col;
    int i4base = blockIdx.x * (CHUNK / 4);
    int E4 = E >> 2;
#pragma unroll
    for (int it = 0; it < CHUNK / 4 / 256; ++it) {
        int i4 = i4base + it * 256 + t;
        if (i4 < E4) {
            int4 c = c4[i4];
            atomicAdd(&sh[c.x >> BKT_SH], 1);
            atomicAdd(&sh[c.y >> BKT_SH], 1);
            atomicAdd(&sh[c.z >> BKT_SH], 1);
            atomicAdd(&sh[c.w >> BKT_SH], 1);
        }
    }
    if (blockIdx.x == 0 && t < (E & 3)) atomicAdd(&sh[col[(E & ~3) + t] >> BKT_SH], 1);
    __syncthreads();
    for (int b = t; b < nbuck; b += 256) lhist[b * nblk + blockIdx.x] = sh[b];
}

// pass 1b: write (col,row) pairs into per-(bucket,block) contiguous runs.

__global__ __launch_bounds__(256) void partition_kernel(const int* __restrict__ row,
                                                        const int* __restrict__ col,
                                                        const int* __restrict__ loff,
                                                        uint2* __restrict__ part,
                                                        int E, int nbuck, int nblk) {
    __shared__ int cur[NBUCK_MAX];
    int t = threadIdx.x;
    for (int b = t; b < nbuck; b += 256) cur[b] = loff[b * nblk + blockIdx.x];
    __syncthreads();
    const int4* c4 = (const int4*)col;
    const int4* r4 = (const int4*)row;
    int i4base = blockIdx.x * (CHUNK / 4);
    int E4 = E >> 2;
#pragma unroll
    for (int it = 0; it < CHUNK / 4 / 256; ++it) {
        int i4 = i4base + it * 256 + t;
        if (i4 < E4) {
            int4 c = c4[i4];
            int4 r = r4[i4];
            int p0 = atomicAdd(&cur[c.x >> BKT_SH], 1); part[p0] = make_uint2((uint)c.x, (uint)r.x);
            int p1 = atomicAdd(&cur[c.y >> BKT_SH], 1); part[p1] = make_uint2((uint)c.y, (uint)r.y);
            int p2 = atomicAdd(&cur[c.z >> BKT_SH], 1); part[p2] = make_uint2((uint)c.z, (uint)r.z);
            int p3 = atomicAdd(&cur[c.w >> BKT_SH], 1); part[p3] = make_uint2((uint)c.w, (uint)r.w);
        }
    }
    if (blockIdx.x == 0 && t < (E & 3)) {
        int e = (E & ~3) + t;
        int c = col[e];
        int p = atomicAdd(&cur[c >> BKT_SH], 1);
        part[p] = make_uint2((uint)c, (uint)row[e]);
    }
}

// pass 2: one block per bucket. Pass A counts the bucket's 128 cols; in-block
// exclusive scan + bucket base (= loff[b*nblk], since the flat scan is
// bucket-major) yields rp and dinv as by-products; pass B scatters csr into
// an ~8KB window (one write per line).

__global__ __launch_bounds__(256) void fill2(const uint2* __restrict__ part,
                                             const int* __restrict__ loff,
                                             int* __restrict__ rp,
                                             float* __restrict__ dinv,
                                             int* __restrict__ csr,
                                             int E, int nbuck, int nblk, int N) {
    __shared__ int lcnt[BKT];
    __shared__ int sc[2][BKT];
    __shared__ int lbase[BKT];
    __shared__ int lcur[BKT];
    int b = blockIdx.x;
    int t = threadIdx.x;
    if (t < BKT) lcnt[t] = 0;
    __syncthreads();

    int beg = b * nblk < nbuck * nblk ? loff[b * nblk] : E;
    int end = (b + 1 < nbuck) ? loff[(b + 1) * nblk] : E;

    // pass A: count cols in this bucket
    for (int e = beg + t; e < end; e += 256) {
        uint2 pr = part[e];
        atomicAdd(&lcnt[(int)pr.x & (BKT - 1)], 1);
    }
    __syncthreads();

    // in-block 128-wide exclusive scan (Hillis-Steele, uniform barriers)
    int myv = (t < BKT) ? lcnt[t] : 0;
    if (t < BKT) sc[0][t] = myv;
    __syncthreads();
    int p = 0;
    for (int d = 1; d < BKT; d <<= 1) {
        if (t < BKT) {
            int val = sc[p][t] + ((t >= d) ? sc[p][t - d] : 0);
            sc[p ^ 1][t] = val;
        }
        p ^= 1;
        __syncthreads();
    }
    if (t < BKT) {
        int base = beg + sc[p][t] - myv;          // absolute csr offset for col c
        lbase[t] = base;
        lcur[t]  = 0;
        int c = (b << BKT_SH) + t;
        if (c <= N)  rp[c] = base;                // rp[N] lands here too (count 0 beyond)
        if (c < N)   dinv[c] = rsqrtf((float)(myv + 1));  // +1 = self loop
    }
    __syncthreads();

    // pass B: scatter
    for (int e = beg + t; e < end; e += 256) {
        uint2 pr = part[e];
        int cl = (int)pr.x & (BKT - 1);
        int slot = atomicAdd(&lcur[cl], 1);
        csr[lbase[cl] + slot] = (int)pr.y;
    }
}

// ---------------- GEMM: out[m][n] = bf16( dinv[m] * sum_k X[m][k] * W[k][n] ) ----------------
// K=128. f32 VALU. X tile 64x(128+pad) in LDS; W staged in 32-k chunks in LDS.
// kc loop ROLLED so barriers bound the scheduler's load-hoisting window (anti-spill).

template <int NC, bool BF16_IN>
__global__ __launch_bounds__(256) void gemm_scale(const void* __restrict__ Xv,
                                                  const float* __restrict__ W,
                                                  const float* __restrict__ dinv,
                                                  uint* __restrict__ out, int M) {
    constexpr int K = 128, BM = 64, PAD = 132, CPT = NC / 16;
    __shared__ float xs[BM * PAD];
    __shared__ float ws[32 * NC];

    int tid = threadIdx.x;
    int block_row = blockIdx.x * BM;

    if (BF16_IN) {
        const uint* X = (const uint*)Xv;
        int r = tid >> 5, c = tid & 31;
#pragma unroll
        for (int p = 0; p < 8; ++p) {
            int rr = r + p * 8;
            int gr = block_row + rr;
            if (gr > M - 1) gr = M - 1;
            uint2 v = *(const uint2*)(X + (size_t)gr * 64 + c * 2);
            float* d = xs + rr * PAD + c * 4;
            d[0] = bf_lo(v.x); d[1] = bf_hi(v.x);
            d[2] = bf_lo(v.y); d[3] = bf_hi(v.y);
        }
    } else {
        const float* X = (const float*)Xv;
        int r = tid >> 5, k4 = tid & 31;
#pragma unroll
        for (int p = 0; p < 8; ++p) {
            int rr = r + p * 8;
            int gr = block_row + rr;
            if (gr > M - 1) gr = M - 1;
            float4 v = *(const float4*)(X + (size_t)gr * K + k4 * 4);
            *(float4*)(xs + rr * PAD + k4 * 4) = v;
        }
    }

    int tc = tid & 15;
    int tr = tid >> 4;

    float acc[4][CPT];
#pragma unroll
    for (int i = 0; i < 4; ++i)
#pragma unroll
        for (int j = 0; j < CPT; ++j) acc[i][j] = 0.0f;

    for (int kc = 0; kc < K / 32; ++kc) {   // ROLLED: barrier bounds sched window
        {
            const float4* src = (const float4*)(W + (size_t)kc * 32 * NC);
            float4* dst = (float4*)ws;
#pragma unroll
            for (int i = 0; i < NC / 32; ++i) dst[tid + i * 256] = src[tid + i * 256];
        }
        __syncthreads();

#pragma unroll 2
        for (int k4 = 0; k4 < 8; ++k4) {
            float4 xa[4];
#pragma unroll
            for (int i = 0; i < 4; ++i)
                xa[i] = *(const float4*)(xs + (tr * 4 + i) * PAD + kc * 32 + k4 * 4);
#pragma unroll
            for (int kk = 0; kk < 4; ++kk) {
                float wv[CPT];
#pragma unroll
                for (int m = 0; m < CPT / 4; ++m) {
                    float4 w4 = *(const float4*)(ws + (k4 * 4 + kk) * NC + tc * CPT + m * 4);
                    wv[m * 4 + 0] = w4.x; wv[m * 4 + 1] = w4.y;
                    wv[m * 4 + 2] = w4.z; wv[m * 4 + 3] = w4.w;
                }
#pragma unroll
                for (int i = 0; i < 4; ++i) {
                    float xv = (&xa[i].x)[kk];
#pragma unroll
                    for (int j = 0; j < CPT; ++j) acc[i][j] = fmaf(xv, wv[j], acc[i][j]);
                }
            }
        }
        __syncthreads();
    }

#pragma unroll
    for (int i = 0; i < 4; ++i) {
        int r = block_row + tr * 4 + i;
        if (r < M) {
            float di = dinv[r];
            if (CPT == 8) {
                uint4 o;
                o.x = pack_bf16(acc[i][0] * di, acc[i][1] * di);
                o.y = pack_bf16(acc[i][2] * di, acc[i][3] * di);
                o.z = pack_bf16(acc[i][4] * di, acc[i][5] * di);
                o.w = pack_bf16(acc[i][6] * di, acc[i][7] * di);
                *(uint4*)(out + (size_t)r * 64 + tc * 4) = o;
            } else {
                uint2 o;
                o.x = pack_bf16(acc[i][0] * di, acc[i][1] * di);
                o.y = pack_bf16(acc[i][2] * di, acc[i][3] * di);
                *(uint2*)(out + (size_t)r * 32 + tc * 2) = o;
            }
        }
    }
}

// ---------------- Aggregation (8-deep gather pipeline) ----------------

__global__ __launch_bounds__(256) void agg128(const uint* __restrict__ xws,
                                              const int* __restrict__ rp,
                                              const int* __restrict__ csr,
                                              const float* __restrict__ dinv,
                                              const float* __restrict__ bias,
                                              uint* __restrict__ h, int n) {
    int gid  = blockIdx.x * 256 + threadIdx.x;
    int node = gid >> 6;
    int lane = gid & 63;
    if (node >= n) return;

    uint self = xws[(size_t)node * 64 + lane];
    float ax = bf_lo(self), ay = bf_hi(self);

    int beg = rp[node], end = rp[node + 1];
    int e = beg;
    for (; e + 8 <= end; e += 8) {
        int s0 = csr[e],     s1 = csr[e + 1], s2 = csr[e + 2], s3 = csr[e + 3];
        int s4 = csr[e + 4], s5 = csr[e + 5], s6 = csr[e + 6], s7 = csr[e + 7];
        uint v0 = xws[(size_t)s0 * 64 + lane];
        uint v1 = xws[(size_t)s1 * 64 + lane];
        uint v2 = xws[(size_t)s2 * 64 + lane];
        uint v3 = xws[(size_t)s3 * 64 + lane];
        uint v4 = xws[(size_t)s4 * 64 + lane];
        uint v5 = xws[(size_t)s5 * 64 + lane];
        uint v6 = xws[(size_t)s6 * 64 + lane];
        uint v7 = xws[(size_t)s7 * 64 + lane];
        ax += bf_lo(v0) + bf_lo(v1) + bf_lo(v2) + bf_lo(v3)
            + bf_lo(v4) + bf_lo(v5) + bf_lo(v6) + bf_lo(v7);
        ay += bf_hi(v0) + bf_hi(v1) + bf_hi(v2) + bf_hi(v3)
            + bf_hi(v4) + bf_hi(v5) + bf_hi(v6) + bf_hi(v7);
    }
    if (e + 4 <= end) {
        int s0 = csr[e], s1 = csr[e + 1], s2 = csr[e + 2], s3 = csr[e + 3];
        uint v0 = xws[(size_t)s0 * 64 + lane];
        uint v1 = xws[(size_t)s1 * 64 + lane];
        uint v2 = xws[(size_t)s2 * 64 + lane];
        uint v3 = xws[(size_t)s3 * 64 + lane];
        ax += bf_lo(v0) + bf_lo(v1) + bf_lo(v2) + bf_lo(v3);
        ay += bf_hi(v0) + bf_hi(v1) + bf_hi(v2) + bf_hi(v3);
        e += 4;
    }
    for (; e < end; ++e) {
        uint v = xws[(size_t)csr[e] * 64 + lane];
        ax += bf_lo(v);
        ay += bf_hi(v);
    }

    float  di = dinv[node];
    float2 b  = ((const float2*)bias)[lane];
    float ox = fmaxf(fmaf(di, ax, b.x), 0.0f);
    float oy = fmaxf(fmaf(di, ay, b.y), 0.0f);
    h[(size_t)node * 64 + lane] = pack_bf16(ox, oy);
}

__global__ __launch_bounds__(256) void agg64(const uint* __restrict__ xws,
                                             const int* __restrict__ rp,
                                             const int* __restrict__ csr,
                                             const float* __restrict__ dinv,
                                             const float* __restrict__ bias,
                                             float* __restrict__ out, int n) {
    int gid  = blockIdx.x * 256 + threadIdx.x;
    int node = gid >> 5;
    int l    = gid & 31;
    if (node >= n) return;

    uint self = xws[(size_t)node * 32 + l];
    float ax = bf_lo(self), ay = bf_hi(self);

    int beg = rp[node], end = rp[node + 1];
    int e = beg;
    for (; e + 8 <= end; e += 8) {
        int s0 = csr[e],     s1 = csr[e + 1], s2 = csr[e + 2], s3 = csr[e + 3];
        int s4 = csr[e + 4], s5 = csr[e + 5], s6 = csr[e + 6], s7 = csr[e + 7];
        uint v0 = xws[(size_t)s0 * 32 + l];
        uint v1 = xws[(size_t)s1 * 32 + l];
        uint v2 = xws[(size_t)s2 * 32 + l];
        uint v3 = xws[(size_t)s3 * 32 + l];
        uint v4 = xws[(size_t)s4 * 32 + l];
        uint v5 = xws[(size_t)s5 * 32 + l];
        uint v6 = xws[(size_t)s6 * 32 + l];
        uint v7 = xws[(size_t)s7 * 32 + l];
        ax += bf_lo(v0) + bf_lo(v1) + bf_lo(v2) + bf_lo(v3)
            + bf_lo(v4) + bf_lo(v5) + bf_lo(v6) + bf_lo(v7);
        ay += bf_hi(v0) + bf_hi(v1) + bf_hi(v2) + bf_hi(v3)
            + bf_hi(v4) + bf_hi(v5) + bf_hi(v6) + bf_hi(v7);
    }
    if (e + 4 <= end) {
        int s0 = csr[e], s1 = csr[e + 1], s2 = csr[e + 2], s3 = csr[e + 3];
        uint v0 = xws[(size_t)s0 * 32 + l];
        uint v1 = xws[(size_t)s1 * 32 + l];
        uint v2 = xws[(size_t)s2 * 32 + l];
        uint v3 = xws[(size_t)s3 * 32 + l];
        ax += bf_lo(v0) + bf_lo(v1) + bf_lo(v2) + bf_lo(v3);
        ay += bf_hi(v0) + bf_hi(v1) + bf_hi(v2) + bf_hi(v3);
        e += 4;
    }
    for (; e < end; ++e) {
        uint v = xws[(size_t)csr[e] * 32 + l];
        ax += bf_lo(v);
        ay += bf_hi(v);
    }

    float  di = dinv[node];
    float2 b  = ((const float2*)bias)[l];
    float2 o;
    o.x = fmaf(di, ax, b.x);
    o.y = fmaf(di, ay, b.y);
    ((float2*)out)[(size_t)node * 32 + l] = o;
}

// ---------------- launch ----------------

static inline size_t align512(size_t x) { return (x + 511) & ~(size_t)511; }

extern "C" void kernel_launch(void* const* d_in, const int* in_sizes, int n_in,
                              void* d_out, int out_size, void* d_ws, size_t ws_size,
                              hipStream_t stream) {
    const float* x   = (const float*)d_in[0];
    const int*   ei  = (const int*)d_in[1];
    const float* W1  = (const float*)d_in[2];
    const float* b1  = (const float*)d_in[3];
    const float* W2  = (const float*)d_in[4];
    const float* b2  = (const float*)d_in[5];
    float*       out = (float*)d_out;

    const int N = in_sizes[0] / 128;   // 100000
    const int E = in_sizes[1] / 2;     // 1600000
    const int* row = ei;
    const int* col = ei + E;

    const int nbuck = (N + BKT - 1) >> BKT_SH;               // 782
    const int nblk  = (E + CHUNK - 1) / CHUNK;               // 98
    const int L     = nbuck * nblk;                          // 76,636

    // workspace carve-up
    char* w = (char*)d_ws;
    size_t off = 0;
    auto take = [&](size_t bytes) { void* p = w + off; off = align512(off + bytes); return p; };
    int*   rp     = (int*)  take((size_t)(N + 1) * 4);
    int*   bsums  = (int*)  take(4096);
    float* dinv   = (float*)take((size_t)N * 4);
    int*   csr    = (int*)  take((size_t)E * 4);
    uint*  xws    = (uint*) take((size_t)N * 64 * 4);   // bf16-packed [N,128] / [N,64]
    uint*  h      = (uint*) take((size_t)N * 64 * 4);   // bf16-packed [N,128]
    (void)ws_size;
    // CSR-build temporaries alias the (not-yet-live) xws / h buffers:
    int*   lhist = (int*)xws;                 // L ints
    int*   loff  = (int*)xws + L + 128;       // L+1 ints
    uint2* part  = (uint2*)h;                 // E pairs (12.8MB <= 25.6MB)

    // bucket partition -> csr, rp, dinv (no memset needed: all buffers fully written)
    bucket_hist<<<nblk, 256, 0, stream>>>(col, lhist, E, nbuck, nblk);
    int nb2 = (L + 1023) / 1024;
    scan_a<<<nb2, 1024, 0, stream>>>(lhist, loff, bsums, L);
    scan_b<<<1, 256, 0, stream>>>(bsums, nb2);
    scan_c<<<(L + 256) / 256, 256, 0, stream>>>(loff, bsums, L, E);
    partition_kernel<<<nblk, 256, 0, stream>>>(row, col, loff, part, E, nbuck, nblk);
    fill2<<<nbuck, 256, 0, stream>>>(part, loff, rp, dinv, csr, E, nbuck, nblk, N);

    // layer 1
    gemm_scale<128, false><<<(N + 63) / 64, 256, 0, stream>>>(x, W1, dinv, xws, N);
    agg128<<<(N + 3) / 4, 256, 0, stream>>>(xws, rp, csr, dinv, b1, h, N);

    // layer 2
    gemm_scale<64, true><<<(N + 63) / 64, 256, 0, stream>>>(h, W2, dinv, xws, N);
    agg64<<<(N + 7) / 8, 256, 0, stream>>>(xws, rp, csr, dinv, b2, out, N);
}

// Round 9
// 324.103 us; speedup vs baseline: 14.3411x; 1.0254x over previous
//
#include <hip/hip_runtime.h>

// GAE encoder: 2-layer GCN on MI355X (gfx950).
// R9: gemm W-read remap (float4 {tc, tc+16} instead of {2tc,2tc+1}) kills the
//     4-way LDS bank conflict (6.4M conflict cycles). agg128: 16-deep gather batch.
//     CSR: scan_c folded into partition/fill2 (loff[i]+bsums[i>>10] inline), CHUNK=8192.
// Pipeline: bucket_hist -> scan_a -> scan_b -> partition -> fill2(rp,dinv,csr)
//           -> [gemm -> agg] x2

typedef unsigned int uint;

#define BKT_SH 7               // 128 cols per bucket
#define BKT    (1 << BKT_SH)
#define NBUCK_MAX 1024
#define CHUNK 8192             // edges per partition block

// ---------- bf16 helpers (bit-level, RNE pack) ----------
__device__ __forceinline__ float bf_lo(uint v) { return __uint_as_float(v << 16); }
__device__ __forceinline__ float bf_hi(uint v) { return __uint_as_float(v & 0xffff0000u); }
__device__ __forceinline__ uint pack_bf16(float x, float y) {
    uint bx = __float_as_uint(x), by = __float_as_uint(y);
    bx += 0x7fffu + ((bx >> 16) & 1u);
    by += 0x7fffu + ((by >> 16) & 1u);
    return (bx >> 16) | (by & 0xffff0000u);
}

// ---------------- exclusive scan: A (per-1024 block) + B (<=256 sums) ----------------
// Consumers add bsums[i>>10] inline (no scan_c pass).

__global__ __launch_bounds__(1024) void scan_a(const int* __restrict__ in,
                                               int* __restrict__ outp,
                                               int* __restrict__ bsums, int n) {
    __shared__ int s[2][1024];
    int t = threadIdx.x;
    int i = blockIdx.x * 1024 + t;
    int v = (i < n) ? in[i] : 0;
    s[0][t] = v;
    __syncthreads();
    int p = 0;
    for (int d = 1; d < 1024; d <<= 1) {
        int val = s[p][t] + ((t >= d) ? s[p][t - d] : 0);
        s[p ^ 1][t] = val;
        p ^= 1;
        __syncthreads();
    }
    if (i < n) outp[i] = s[p][t] - v;
    if (t == 1023) bsums[blockIdx.x] = s[p][t];
}

__global__ __launch_bounds__(256) void scan_b(int* __restrict__ bsums, int nb) {
    __shared__ int s[2][256];
    int t = threadIdx.x;
    int v = (t < nb) ? bsums[t] : 0;
    s[0][t] = v;
    __syncthreads();
    int p = 0;
    for (int d = 1; d < 256; d <<= 1) {
        int val = s[p][t] + ((t >= d) ? s[p][t - d] : 0);
        s[p ^ 1][t] = val;
        p ^= 1;
        __syncthreads();
    }
    if (t < nb) bsums[t] = s[p][t] - v;
}

// ---------------- bucket partition CSR build ----------------

__global__ __launch_bounds__(256) void bucket_hist(const int* __restrict__ col,
                                                   int* __restrict__ lhist,
                                                   int E, int nbuck, int nblk) {
    __shared__ int sh[NBUCK_MAX];
    int t = threadIdx.x;
    for (int b = t; b < nbuck; b += 256) sh[b] = 0;
    __syncthreads();
    const int4* c4 = (const int4*)col;
    int i4base = blockIdx.x * (CHUNK / 4);
    int E4 = E >> 2;
#pragma unroll
    for (int it = 0; it < CHUNK / 4 / 256; ++it) {
        int i4 = i4base + it * 256 + t;
        if (i4 < E4) {
            int4 c = c4[i4];
            atomicAdd(&sh[c.x >> BKT_SH], 1);
            atomicAdd(&sh[c.y >> BKT_SH], 1);
            atomicAdd(&sh[c.z >> BKT_SH], 1);
            atomicAdd(&sh[c.w >> BKT_SH], 1);
        }
    }
    if (blockIdx.x == 0 && t < (E & 3)) atomicAdd(&sh[col[(E & ~3) + t] >> BKT_SH], 1);
    __syncthreads();
    for (int b = t; b < nbuck; b += 256) lhist[b * nblk + blockIdx.x] = sh[b];
}

__global__ __launch_bounds__(256) void partition_kernel(const int* __restrict__ row,
                                                        const int* __restrict__ col,
                                                        const int* __restrict__ loff,
                                                        const int* __restrict__ bsums,
                                                        uint2* __restrict__ part,
                                                        int E, int nbuck, int nblk) {
    __shared__ int cur[NBUCK_MAX];
    int t = threadIdx.x;
    for (int b = t; b < nbuck; b += 256) {
        int idx = b * nblk + blockIdx.x;
        cur[b] = loff[idx] + bsums[idx >> 10];
    }
    __syncthreads();
    const int4* c4 = (const int4*)col;
    const int4* r4 = (const int4*)row;
    int i4base = blockIdx.x * (CHUNK / 4);
    int E4 = E >> 2;
#pragma unroll
    for (int it = 0; it < CHUNK / 4 / 256; ++it) {
        int i4 = i4base + it * 256 + t;
        if (i4 < E4) {
            int4 c = c4[i4];
            int4 r = r4[i4];
            int p0 = atomicAdd(&cur[c.x >> BKT_SH], 1); part[p0] = make_uint2((uint)c.x, (uint)r.x);
            int p1 = atomicAdd(&cur[c.y >> BKT_SH], 1); part[p1] = make_uint2((uint)c.y, (uint)r.y);
            int p2 = atomicAdd(&cur[c.z >> BKT_SH], 1); part[p2] = make_uint2((uint)c.z, (uint)r.z);
            int p3 = atomicAdd(&cur[c.w >> BKT_SH], 1); part[p3] = make_uint2((uint)c.w, (uint)r.w);
        }
    }
    if (blockIdx.x == 0 && t < (E & 3)) {
        int e = (E & ~3) + t;
        int c = col[e];
        int p = atomicAdd(&cur[c >> BKT_SH], 1);
        part[p] = make_uint2((uint)c, (uint)row[e]);
    }
}

// one block per bucket: count 128 cols -> in-block scan -> rp/dinv by-products -> scatter csr.

__global__ __launch_bounds__(256) void fill2(const uint2* __restrict__ part,
                                             const int* __restrict__ loff,
                                             const int* __restrict__ bsums,
                                             int* __restrict__ rp,
                                             float* __restrict__ dinv,
                                             int* __restrict__ csr,
                                             int E, int nbuck, int nblk, int N) {
    __shared__ int lcnt[BKT];
    __shared__ int sc[2][BKT];
    __shared__ int lbase[BKT];
    __shared__ int lcur[BKT];
    int b = blockIdx.x;
    int t = threadIdx.x;
    if (t < BKT) lcnt[t] = 0;
    __syncthreads();

    int i0  = b * nblk;
    int beg = loff[i0] + bsums[i0 >> 10];
    int end = E;
    if (b + 1 < nbuck) {
        int i1 = (b + 1) * nblk;
        end = loff[i1] + bsums[i1 >> 10];
    }

    for (int e = beg + t; e < end; e += 256) {
        uint2 pr = part[e];
        atomicAdd(&lcnt[(int)pr.x & (BKT - 1)], 1);
    }
    __syncthreads();

    int myv = (t < BKT) ? lcnt[t] : 0;
    if (t < BKT) sc[0][t] = myv;
    __syncthreads();
    int p = 0;
    for (int d = 1; d < BKT; d <<= 1) {
        if (t < BKT) {
            int val = sc[p][t] + ((t >= d) ? sc[p][t - d] : 0);
            sc[p ^ 1][t] = val;
        }
        p ^= 1;
        __syncthreads();
    }
    if (t < BKT) {
        int base = beg + sc[p][t] - myv;
        lbase[t] = base;
        lcur[t]  = 0;
        int c = (b << BKT_SH) + t;
        if (c <= N)  rp[c] = base;
        if (c < N)   dinv[c] = rsqrtf((float)(myv + 1));  // +1 = self loop
    }
    __syncthreads();

    for (int e = beg + t; e < end; e += 256) {
        uint2 pr = part[e];
        int cl = (int)pr.x & (BKT - 1);
        int slot = atomicAdd(&lcur[cl], 1);
        csr[lbase[cl] + slot] = (int)pr.y;
    }
}

// ---------------- GEMM: out[m][n] = bf16( dinv[m] * sum_k X[m][k] * W[k][n] ) ----------------
// K=128. f32 VALU. X tile 64x(128+pad) in LDS; W staged in 32-k chunks in LDS.
// W fragment per thread = float4s {tc, tc+16} (stride-1 across lanes -> 2-way bank
// alias = free), NOT {2tc,2tc+1} (4-way conflict, was 6.4M conflict cycles).
// kc loop ROLLED so barriers bound the scheduler's load-hoisting window (anti-spill).

template <int NC, bool BF16_IN>
__global__ __launch_bounds__(256) void gemm_scale(const void* __restrict__ Xv,
                                                  const float* __restrict__ W,
                                                  const float* __restrict__ dinv,
                                                  uint* __restrict__ out, int M) {
    constexpr int K = 128, BM = 64, PAD = 132, CPT = NC / 16;
    __shared__ float xs[BM * PAD];
    __shared__ float ws[32 * NC];

    int tid = threadIdx.x;
    int block_row = blockIdx.x * BM;

    if (BF16_IN) {
        const uint* X = (const uint*)Xv;
        int r = tid >> 5, c = tid & 31;
#pragma unroll
        for (int p = 0; p < 8; ++p) {
            int rr = r + p * 8;
            int gr = block_row + rr;
            if (gr > M - 1) gr = M - 1;
            uint2 v = *(const uint2*)(X + (size_t)gr * 64 + c * 2);
            float* d = xs + rr * PAD + c * 4;
            d[0] = bf_lo(v.x); d[1] = bf_hi(v.x);
            d[2] = bf_lo(v.y); d[3] = bf_hi(v.y);
        }
    } else {
        const float* X = (const float*)Xv;
        int r = tid >> 5, k4 = tid & 31;
#pragma unroll
        for (int p = 0; p < 8; ++p) {
            int rr = r + p * 8;
            int gr = block_row + rr;
            if (gr > M - 1) gr = M - 1;
            float4 v = *(const float4*)(X + (size_t)gr * K + k4 * 4);
            *(float4*)(xs + rr * PAD + k4 * 4) = v;
        }
    }

    int tc = tid & 15;
    int tr = tid >> 4;

    float acc[4][CPT];
#pragma unroll
    for (int i = 0; i < 4; ++i)
#pragma unroll
        for (int j = 0; j < CPT; ++j) acc[i][j] = 0.0f;

    for (int kc = 0; kc < K / 32; ++kc) {   // ROLLED: barrier bounds sched window
        {
            const float4* src = (const float4*)(W + (size_t)kc * 32 * NC);
            float4* dst = (float4*)ws;
#pragma unroll
            for (int i = 0; i < NC / 32; ++i) dst[tid + i * 256] = src[tid + i * 256];
        }
        __syncthreads();

#pragma unroll 2
        for (int k4 = 0; k4 < 8; ++k4) {
            float4 xa[4];
#pragma unroll
            for (int i = 0; i < 4; ++i)
                xa[i] = *(const float4*)(xs + (tr * 4 + i) * PAD + kc * 32 + k4 * 4);
#pragma unroll
            for (int kk = 0; kk < 4; ++kk) {
                float wv[CPT];
#pragma unroll
                for (int m = 0; m < CPT / 4; ++m) {
                    // float4 index tc + m*16: stride-1 across the 16 tc lanes
                    float4 w4 = *(const float4*)(ws + (k4 * 4 + kk) * NC + (tc + m * 16) * 4);
                    wv[m * 4 + 0] = w4.x; wv[m * 4 + 1] = w4.y;
                    wv[m * 4 + 2] = w4.z; wv[m * 4 + 3] = w4.w;
                }
#pragma unroll
                for (int i = 0; i < 4; ++i) {
                    float xv = (&xa[i].x)[kk];
#pragma unroll
                    for (int j = 0; j < CPT; ++j) acc[i][j] = fmaf(xv, wv[j], acc[i][j]);
                }
            }
        }
        __syncthreads();
    }

    // epilogue: thread's cols are 4*(tc+m*16)..+3 for m in [0, CPT/4)
#pragma unroll
    for (int i = 0; i < 4; ++i) {
        int r = block_row + tr * 4 + i;
        if (r < M) {
            float di = dinv[r];
#pragma unroll
            for (int m = 0; m < CPT / 4; ++m) {
                uint2 o;
                o.x = pack_bf16(acc[i][m * 4 + 0] * di, acc[i][m * 4 + 1] * di);
                o.y = pack_bf16(acc[i][m * 4 + 2] * di, acc[i][m * 4 + 3] * di);
                *(uint2*)(out + (size_t)r * (NC / 2) + (tc + m * 16) * 2) = o;
            }
        }
    }
}

// ---------------- Aggregation (16/8/4-deep gather pipeline) ----------------

__global__ __launch_bounds__(256) void agg128(const uint* __restrict__ xws,
                                              const int* __restrict__ rp,
                                              const int* __restrict__ csr,
                                              const float* __restrict__ dinv,
                                              const float* __restrict__ bias,
                                              uint* __restrict__ h, int n) {
    int gid  = blockIdx.x * 256 + threadIdx.x;
    int node = gid >> 6;
    int lane = gid & 63;
    if (node >= n) return;

    uint self = xws[(size_t)node * 64 + lane];
    float ax = bf_lo(self), ay = bf_hi(self);

    int beg = rp[node], end = rp[node + 1];
    int e = beg;
    for (; e + 16 <= end; e += 16) {
        int s[16];
#pragma unroll
        for (int q = 0; q < 16; ++q) s[q] = csr[e + q];
        uint v[16];
#pragma unroll
        for (int q = 0; q < 16; ++q) v[q] = xws[(size_t)s[q] * 64 + lane];
#pragma unroll
        for (int q = 0; q < 16; ++q) { ax += bf_lo(v[q]); ay += bf_hi(v[q]); }
    }
    if (e + 8 <= end) {
        int s[8];
#pragma unroll
        for (int q = 0; q < 8; ++q) s[q] = csr[e + q];
        uint v[8];
#pragma unroll
        for (int q = 0; q < 8; ++q) v[q] = xws[(size_t)s[q] * 64 + lane];
#pragma unroll
        for (int q = 0; q < 8; ++q) { ax += bf_lo(v[q]); ay += bf_hi(v[q]); }
        e += 8;
    }
    if (e + 4 <= end) {
        int s0 = csr[e], s1 = csr[e + 1], s2 = csr[e + 2], s3 = csr[e + 3];
        uint v0 = xws[(size_t)s0 * 64 + lane];
        uint v1 = xws[(size_t)s1 * 64 + lane];
        uint v2 = xws[(size_t)s2 * 64 + lane];
        uint v3 = xws[(size_t)s3 * 64 + lane];
        ax += bf_lo(v0) + bf_lo(v1) + bf_lo(v2) + bf_lo(v3);
        ay += bf_hi(v0) + bf_hi(v1) + bf_hi(v2) + bf_hi(v3);
        e += 4;
    }
    for (; e < end; ++e) {
        uint v = xws[(size_t)csr[e] * 64 + lane];
        ax += bf_lo(v);
        ay += bf_hi(v);
    }

    float  di = dinv[node];
    float2 b  = ((const float2*)bias)[lane];
    float ox = fmaxf(fmaf(di, ax, b.x), 0.0f);
    float oy = fmaxf(fmaf(di, ay, b.y), 0.0f);
    h[(size_t)node * 64 + lane] = pack_bf16(ox, oy);
}

__global__ __launch_bounds__(256) void agg64(const uint* __restrict__ xws,
                                             const int* __restrict__ rp,
                                             const int* __restrict__ csr,
                                             const float* __restrict__ dinv,
                                             const float* __restrict__ bias,
                                             float* __restrict__ out, int n) {
    int gid  = blockIdx.x * 256 + threadIdx.x;
    int node = gid >> 5;
    int l    = gid & 31;
    if (node >= n) return;

    uint self = xws[(size_t)node * 32 + l];
    float ax = bf_lo(self), ay = bf_hi(self);

    int beg = rp[node], end = rp[node + 1];
    int e = beg;
    for (; e + 8 <= end; e += 8) {
        int s[8];
#pragma unroll
        for (int q = 0; q < 8; ++q) s[q] = csr[e + q];
        uint v[8];
#pragma unroll
        for (int q = 0; q < 8; ++q) v[q] = xws[(size_t)s[q] * 32 + l];
#pragma unroll
        for (int q = 0; q < 8; ++q) { ax += bf_lo(v[q]); ay += bf_hi(v[q]); }
    }
    if (e + 4 <= end) {
        int s0 = csr[e], s1 = csr[e + 1], s2 = csr[e + 2], s3 = csr[e + 3];
        uint v0 = xws[(size_t)s0 * 32 + l];
        uint v1 = xws[(size_t)s1 * 32 + l];
        uint v2 = xws[(size_t)s2 * 32 + l];
        uint v3 = xws[(size_t)s3 * 32 + l];
        ax += bf_lo(v0) + bf_lo(v1) + bf_lo(v2) + bf_lo(v3);
        ay += bf_hi(v0) + bf_hi(v1) + bf_hi(v2) + bf_hi(v3);
        e += 4;
    }
    for (; e < end; ++e) {
        uint v = xws[(size_t)csr[e] * 32 + l];
        ax += bf_lo(v);
        ay += bf_hi(v);
    }

    float  di = dinv[node];
    float2 b  = ((const float2*)bias)[l];
    float2 o;
    o.x = fmaf(di, ax, b.x);
    o.y = fmaf(di, ay, b.y);
    ((float2*)out)[(size_t)node * 32 + l] = o;
}

// ---------------- launch ----------------

static inline size_t align512(size_t x) { return (x + 511) & ~(size_t)511; }

extern "C" void kernel_launch(void* const* d_in, const int* in_sizes, int n_in,
                              void* d_out, int out_size, void* d_ws, size_t ws_size,
                              hipStream_t stream) {
    const float* x   = (const float*)d_in[0];
    const int*   ei  = (const int*)d_in[1];
    const float* W1  = (const float*)d_in[2];
    const float* b1  = (const float*)d_in[3];
    const float* W2  = (const float*)d_in[4];
    const float* b2  = (const float*)d_in[5];
    float*       out = (float*)d_out;

    const int N = in_sizes[0] / 128;   // 100000
    const int E = in_sizes[1] / 2;     // 1600000
    const int* row = ei;
    const int* col = ei + E;

    const int nbuck = (N + BKT - 1) >> BKT_SH;               // 782
    const int nblk  = (E + CHUNK - 1) / CHUNK;               // 196
    const int L     = nbuck * nblk;                          // 153,272

    // workspace carve-up
    char* w = (char*)d_ws;
    size_t off = 0;
    auto take = [&](size_t bytes) { void* p = w + off; off = align512(off + bytes); return p; };
    int*   rp     = (int*)  take((size_t)(N + 1) * 4);
    int*   bsums  = (int*)  take(4096);
    float* dinv   = (float*)take((size_t)N * 4);
    int*   csr    = (int*)  take((size_t)E * 4);
    uint*  xws    = (uint*) take((size_t)N * 64 * 4);   // bf16-packed [N,128] / [N,64]
    uint*  h      = (uint*) take((size_t)N * 64 * 4);   // bf16-packed [N,128]
    (void)ws_size;
    // CSR-build temporaries alias the (not-yet-live) xws / h buffers:
    int*   lhist = (int*)xws;                 // L ints
    int*   loff  = (int*)xws + L + 128;       // L ints (block-local exclusive scan)
    uint2* part  = (uint2*)h;                 // E pairs (12.8MB <= 25.6MB)

    // bucket partition -> csr, rp, dinv (no memset: all buffers fully written)
    bucket_hist<<<nblk, 256, 0, stream>>>(col, lhist, E, nbuck, nblk);
    int nb2 = (L + 1023) / 1024;              // 150 <= 256
    scan_a<<<nb2, 1024, 0, stream>>>(lhist, loff, bsums, L);
    scan_b<<<1, 256, 0, stream>>>(bsums, nb2);
    partition_kernel<<<nblk, 256, 0, stream>>>(row, col, loff, bsums, part, E, nbuck, nblk);
    fill2<<<nbuck, 256, 0, stream>>>(part, loff, bsums, rp, dinv, csr, E, nbuck, nblk, N);

    // layer 1
    gemm_scale<128, false><<<(N + 63) / 64, 256, 0, stream>>>(x, W1, dinv, xws, N);
    agg128<<<(N + 3) / 4, 256, 0, stream>>>(xws, rp, csr, dinv, b1, h, N);

    // layer 2
    gemm_scale<64, true><<<(N + 63) / 64, 256, 0, stream>>>(h, W2, dinv, xws, N);
    agg64<<<(N + 7) / 8, 256, 0, stream>>>(xws, rp, csr, dinv, b2, out, N);
}